// Round 1
// baseline (566.196 us; speedup 1.0000x reference)
//
#include <hip/hip_runtime.h>

#define LOG2E 1.4426950408889634f

// fast silu: x * sigmoid(x) = x / (1 + exp(-x)), exp via v_exp_f32, div via v_rcp_f32.
// Accuracy ~1e-6 rel — far inside the harness threshold.
__device__ __forceinline__ float fast_silu(float x) {
    float e = __builtin_amdgcn_exp2f(-LOG2E * x);
    return x * __builtin_amdgcn_rcpf(1.0f + e);
}

// ---------------------------------------------------------------------------
// Kernel 1: qW = q @ W.   q: [4096, 256], W: [256, 256], qW: [4096, 256]
// 512 blocks x 256 threads; each block does 8 rows, each thread owns one col.
// ---------------------------------------------------------------------------
__global__ __launch_bounds__(256) void qw_gemm_kernel(
    const float* __restrict__ q, const float* __restrict__ W,
    float* __restrict__ qW)
{
    __shared__ float qs[8 * 256];
    const int tid = threadIdx.x;
    const int rowBase = blockIdx.x * 8;
    const float* qb = q + (size_t)rowBase * 256;

    // stage 8 rows of q (coalesced float4)
    for (int s = tid; s < 8 * 64; s += 256)
        ((float4*)qs)[s] = ((const float4*)qb)[s];
    __syncthreads();

    float acc[8] = {0.f, 0.f, 0.f, 0.f, 0.f, 0.f, 0.f, 0.f};
    for (int k = 0; k < 256; k += 4) {
        // coalesced across tid; W stays hot in L2
        float w0 = W[(k + 0) * 256 + tid];
        float w1v = W[(k + 1) * 256 + tid];
        float w2v = W[(k + 2) * 256 + tid];
        float w3v = W[(k + 3) * 256 + tid];
        #pragma unroll
        for (int r = 0; r < 8; ++r) {
            // uniform address -> LDS broadcast, no bank conflict
            float4 qv = *(const float4*)&qs[r * 256 + k];
            acc[r] += qv.x * w0 + qv.y * w1v + qv.z * w2v + qv.w * w3v;
        }
    }
    for (int r = 0; r < 8; ++r)
        qW[(size_t)(rowBase + r) * 256 + tid] = acc[r];
}

// ---------------------------------------------------------------------------
// Kernel 2: fused bilinear + geo-MLP + masking.
// Grid (64 k-tiles, 64 q-tiles, 4 batches), 256 threads = one 16x16 out tile,
// one output element per thread.
// LDS rows padded to stride 260 floats: 260%32==4 -> bank spread, rows stay
// 16B-aligned for ds_read_b128.
// ---------------------------------------------------------------------------
#define LDS_STRIDE 260

__global__ __launch_bounds__(256) void edge_head_kernel(
    const float* __restrict__ qW, const float* __restrict__ q,
    const float* __restrict__ coords, const int* __restrict__ amask,
    const float* __restrict__ w1, const float* __restrict__ b1,
    const float* __restrict__ w2, const float* __restrict__ b2,
    const float* __restrict__ w3, const float* __restrict__ b3,
    const float* __restrict__ bias, float* __restrict__ out)
{
    __shared__ float qWs[16 * LDS_STRIDE];
    __shared__ float qks[16 * LDS_STRIDE];
    __shared__ float cqx[16], cqy[16], ckx[16], cky[16];
    __shared__ int mq[16], mk[16];

    const int tid = threadIdx.x;
    const int bk = blockIdx.x;   // k tile
    const int bq = blockIdx.y;   // q tile
    const int bb = blockIdx.z;   // batch

    const float* qWb = qW + (size_t)(bb * 1024 + bq * 16) * 256;
    const float* qkb = q  + (size_t)(bb * 1024 + bk * 16) * 256;
    for (int s = tid; s < 16 * 64; s += 256) {
        int row = s >> 6, c4 = s & 63;
        *(float4*)&qWs[row * LDS_STRIDE + c4 * 4] = ((const float4*)qWb)[s];
        *(float4*)&qks[row * LDS_STRIDE + c4 * 4] = ((const float4*)qkb)[s];
    }
    if (tid < 16) {
        int qi = bb * 1024 + bq * 16 + tid;
        int ki = bb * 1024 + bk * 16 + tid;
        cqx[tid] = coords[qi * 2 + 0];
        cqy[tid] = coords[qi * 2 + 1];
        ckx[tid] = coords[ki * 2 + 0];
        cky[tid] = coords[ki * 2 + 1];
        mq[tid] = amask[qi];
        mk[tid] = amask[ki];
    }
    __syncthreads();

    const int tx = tid & 15;   // k within tile
    const int ty = tid >> 4;   // q within tile

    // ---- bilinear: dot(qW[q,:], q[k,:]) over 256 ----
    float bil = 0.f;
    #pragma unroll 4
    for (int kk = 0; kk < 256; kk += 4) {
        float4 a = *(const float4*)&qWs[ty * LDS_STRIDE + kk];
        float4 c = *(const float4*)&qks[tx * LDS_STRIDE + kk];
        bil += a.x * c.x + a.y * c.y + a.z * c.z + a.w * c.w;
    }

    // ---- geometry features ----
    float dx = cqx[ty] - ckx[tx];
    float dy = cqy[ty] - cky[tx];
    float dist2 = dx * dx + dy * dy;
    float dist = sqrtf(dist2 + 1e-8f);
    bool mz = (fabsf(dx) < 1e-6f) && (fabsf(dy) < 1e-6f);
    float dxs = mz ? 1e-6f : dx;
    float dys = mz ? 1e-6f : dy;
    // sin(atan2(dys,dxs)) = dys * rsqrt(dxs^2+dys^2); same for cos
    float rinv = __builtin_amdgcn_rsqf(dxs * dxs + dys * dys);
    float sv = dys * rinv;
    float cv = dxs * rinv;

    // ---- MLP: 6 -> 64 -> 64 -> 1, silu activations ----
    // w2 indices are wave-uniform -> compiler scalarizes to s_load.
    float h2[64];
    #pragma unroll
    for (int j = 0; j < 64; ++j) h2[j] = b2[j];

    for (int i = 0; i < 64; ++i) {
        float h = b1[i]
                + dx    * w1[0 * 64 + i]
                + dy    * w1[1 * 64 + i]
                + dist  * w1[2 * 64 + i]
                + dist2 * w1[3 * 64 + i]
                + sv    * w1[4 * 64 + i]
                + cv    * w1[5 * 64 + i];
        float s = fast_silu(h);
        const float* w2row = w2 + i * 64;
        #pragma unroll
        for (int j = 0; j < 64; ++j) h2[j] += s * w2row[j];
    }

    float geo = b3[0];
    #pragma unroll
    for (int j = 0; j < 64; ++j) geo += fast_silu(h2[j]) * w3[j];

    // ---- combine + diag + mask ----
    int qi = bq * 16 + ty;
    int ki = bk * 16 + tx;
    float logit = bil + geo + bias[0];
    if (qi == ki) logit = 0.f;
    if (!(mq[ty] != 0 && mk[tx] != 0)) logit = -1e9f;

    out[(size_t)((bb << 10) + qi) * 1024 + ki] = logit;
}

extern "C" void kernel_launch(void* const* d_in, const int* in_sizes, int n_in,
                              void* d_out, int out_size, void* d_ws, size_t ws_size,
                              hipStream_t stream) {
    const float* q      = (const float*)d_in[0];   // [4,1024,256]
    const float* coords = (const float*)d_in[1];   // [4,1024,2]
    const int*   amask  = (const int*)d_in[2];     // [4,1024] bool -> int32
    const float* W      = (const float*)d_in[3];   // [256,256]
    const float* w1     = (const float*)d_in[4];   // [6,64]
    const float* b1     = (const float*)d_in[5];   // [64]
    const float* w2     = (const float*)d_in[6];   // [64,64]
    const float* b2     = (const float*)d_in[7];   // [64]
    const float* w3     = (const float*)d_in[8];   // [64,1]
    const float* b3     = (const float*)d_in[9];   // [1]
    const float* bias   = (const float*)d_in[10];  // [1]
    float* out = (float*)d_out;

    float* qW = (float*)d_ws;  // 4096*256 floats = 4 MB scratch

    qw_gemm_kernel<<<dim3(512), dim3(256), 0, stream>>>(q, W, qW);
    edge_head_kernel<<<dim3(64, 64, 4), dim3(256), 0, stream>>>(
        qW, q, coords, amask, w1, b1, w2, b2, w3, b3, bias, out);
}

// Round 2
// 346.750 us; speedup vs baseline: 1.6329x; 1.6329x over previous
//
#include <hip/hip_runtime.h>

#define LOG2E 1.4426950408889634f

typedef __bf16 bf16x8 __attribute__((ext_vector_type(8)));
typedef float f32x4 __attribute__((ext_vector_type(4)));

__device__ __forceinline__ float fast_silu(float x) {
    float e = __builtin_amdgcn_exp2f(-LOG2E * x);
    return x * __builtin_amdgcn_rcpf(1.0f + e);
}

// float -> bf16 bits (round-half-up; plenty accurate for this threshold)
__device__ __forceinline__ unsigned short f2bf(float f) {
    union { float f; unsigned u; } v; v.f = f;
    return (unsigned short)((v.u + 0x8000u) >> 16);
}

// ---------------------------------------------------------------------------
// Kernel 1: qW = q @ W.   q: [4096, 256], W: [256, 256], qW: [4096, 256]
// ---------------------------------------------------------------------------
__global__ __launch_bounds__(256) void qw_gemm_kernel(
    const float* __restrict__ q, const float* __restrict__ W,
    float* __restrict__ qW)
{
    __shared__ float qs[8 * 256];
    const int tid = threadIdx.x;
    const int rowBase = blockIdx.x * 8;
    const float* qb = q + (size_t)rowBase * 256;

    for (int s = tid; s < 8 * 64; s += 256)
        ((float4*)qs)[s] = ((const float4*)qb)[s];
    __syncthreads();

    float acc[8] = {0.f, 0.f, 0.f, 0.f, 0.f, 0.f, 0.f, 0.f};
    for (int k = 0; k < 256; k += 4) {
        float w0 = W[(k + 0) * 256 + tid];
        float w1v = W[(k + 1) * 256 + tid];
        float w2v = W[(k + 2) * 256 + tid];
        float w3v = W[(k + 3) * 256 + tid];
        #pragma unroll
        for (int r = 0; r < 8; ++r) {
            float4 qv = *(const float4*)&qs[r * 256 + k];
            acc[r] += qv.x * w0 + qv.y * w1v + qv.z * w2v + qv.w * w3v;
        }
    }
    for (int r = 0; r < 8; ++r)
        qW[(size_t)(rowBase + r) * 256 + tid] = acc[r];
}

// ---------------------------------------------------------------------------
// Kernel 2: fused bilinear(MFMA) + geo-MLP(layer1 VALU, layer2 MFMA) + mask.
// Block = 256 threads (4 waves) = one 16x16 pair tile, pair p=tid,
// q_local = p&15, k_local = p>>4.
// MFMA 16x16x32 bf16 layouts (m89/m120-verified):
//   A[row=lane&15][k=quad*8+j], B[k=quad*8+j][col=lane&15],
//   C[row=quad*4+reg][col=lane&15]
// ---------------------------------------------------------------------------
#define QW_STRIDE 264   // ushorts (256+8 pad): 528B rows, 16B-aligned, 4-dword bank skew
#define H1_STRIDE 72    // ushorts (64+8 pad): 144B rows, 16B-aligned, 4-dword bank skew

__global__ __launch_bounds__(256) void edge_head_kernel(
    const float* __restrict__ qW, const float* __restrict__ q,
    const float* __restrict__ coords, const int* __restrict__ amask,
    const float* __restrict__ w1, const float* __restrict__ b1,
    const float* __restrict__ w2, const float* __restrict__ b2,
    const float* __restrict__ w3, const float* __restrict__ b3,
    const float* __restrict__ bias, float* __restrict__ out)
{
    __shared__ unsigned short qWs[16 * QW_STRIDE];
    __shared__ unsigned short qks[16 * QW_STRIDE];
    __shared__ unsigned short h1s[256 * H1_STRIDE];
    __shared__ float bils[16 * 17];
    __shared__ float gs[16 * 17];
    __shared__ float cqx[16], cqy[16], ckx[16], cky[16];
    __shared__ int mq[16], mk[16];

    const int tid  = threadIdx.x;
    const int lane = tid & 63;
    const int wv   = tid >> 6;
    const int l15  = lane & 15;
    const int quad = lane >> 4;
    const int bk = blockIdx.x, bq = blockIdx.y, bb = blockIdx.z;

    // ---- preload w2 B-fragments + b2/w3 columns (issued early; L1-hot) ----
    bf16x8 bfrag[4][2];
    float b2c[4], w3c[4];
    #pragma unroll
    for (int n = 0; n < 4; ++n) {
        b2c[n] = b2[16 * n + l15];
        w3c[n] = w3[16 * n + l15];
        #pragma unroll
        for (int s = 0; s < 2; ++s) {
            union { unsigned short u[8]; bf16x8 v; } tmp;
            #pragma unroll
            for (int j = 0; j < 8; ++j)
                tmp.u[j] = f2bf(w2[(32 * s + 8 * quad + j) * 64 + 16 * n + l15]);
            bfrag[n][s] = tmp.v;
        }
    }

    // ---- stage qW / q tiles as bf16 ----
    const float* qWb = qW + (size_t)(bb * 1024 + bq * 16) * 256;
    const float* qkb = q  + (size_t)(bb * 1024 + bk * 16) * 256;
    #pragma unroll
    for (int it = 0; it < 4; ++it) {
        int s = tid + it * 256;        // float4 index, 0..1023
        int row = s >> 6, c4 = s & 63;
        float4 a = ((const float4*)qWb)[s];
        float4 b = ((const float4*)qkb)[s];
        ushort4 ua = make_ushort4(f2bf(a.x), f2bf(a.y), f2bf(a.z), f2bf(a.w));
        ushort4 ub = make_ushort4(f2bf(b.x), f2bf(b.y), f2bf(b.z), f2bf(b.w));
        *(ushort4*)&qWs[row * QW_STRIDE + c4 * 4] = ua;
        *(ushort4*)&qks[row * QW_STRIDE + c4 * 4] = ub;
    }
    if (tid < 16) {
        int qi = bb * 1024 + bq * 16 + tid;
        int ki = bb * 1024 + bk * 16 + tid;
        cqx[tid] = coords[qi * 2 + 0]; cqy[tid] = coords[qi * 2 + 1];
        ckx[tid] = coords[ki * 2 + 0]; cky[tid] = coords[ki * 2 + 1];
        mq[tid] = amask[qi]; mk[tid] = amask[ki];
    }
    __syncthreads();

    // ---- per-thread: features + layer1 + silu -> h1s (bf16, A-layout rows) ----
    {
        const int ql = tid & 15, kl = tid >> 4;
        float dx = cqx[ql] - ckx[kl];
        float dy = cqy[ql] - cky[kl];
        float dist2 = dx * dx + dy * dy;
        float dist = sqrtf(dist2 + 1e-8f);
        bool mz = (fabsf(dx) < 1e-6f) && (fabsf(dy) < 1e-6f);
        float dxs = mz ? 1e-6f : dx;
        float dys = mz ? 1e-6f : dy;
        float rinv = __builtin_amdgcn_rsqf(dxs * dxs + dys * dys);
        float sv = dys * rinv;   // sin(atan2(dys,dxs))
        float cv = dxs * rinv;   // cos(atan2(dys,dxs))

        unsigned short* hrow = &h1s[tid * H1_STRIDE];
        #pragma unroll 4
        for (int i = 0; i < 64; i += 2) {
            float h0 = b1[i]     + dx * w1[i]       + dy * w1[64 + i]
                     + dist * w1[128 + i] + dist2 * w1[192 + i]
                     + sv * w1[256 + i]   + cv * w1[320 + i];
            float h1v = b1[i+1]  + dx * w1[i+1]     + dy * w1[65 + i]
                     + dist * w1[129 + i] + dist2 * w1[193 + i]
                     + sv * w1[257 + i]   + cv * w1[321 + i];
            unsigned pk = (unsigned)f2bf(fast_silu(h0))
                        | ((unsigned)f2bf(fast_silu(h1v)) << 16);
            *(unsigned*)&hrow[i] = pk;
        }
    }
    __syncthreads();

    // ---- bilinear via MFMA (wave 0 only: 8 MFMA, K=256) ----
    if (wv == 0) {
        f32x4 accb = {0.f, 0.f, 0.f, 0.f};
        #pragma unroll
        for (int s = 0; s < 8; ++s) {
            bf16x8 a = *(const bf16x8*)&qWs[l15 * QW_STRIDE + 32 * s + 8 * quad];
            bf16x8 b = *(const bf16x8*)&qks[l15 * QW_STRIDE + 32 * s + 8 * quad];
            accb = __builtin_amdgcn_mfma_f32_16x16x32_bf16(a, b, accb, 0, 0, 0);
        }
        #pragma unroll
        for (int r = 0; r < 4; ++r)
            bils[(quad * 4 + r) * 17 + l15] = accb[r];
    }

    // ---- layer2 via MFMA: each wave owns 4 M-tiles (k_local columns) ----
    #pragma unroll
    for (int tt = 0; tt < 4; ++tt) {
        int t = wv * 4 + tt;   // k_local of this M-tile
        const unsigned short* arow = &h1s[(t * 16 + l15) * H1_STRIDE];
        bf16x8 a0 = *(const bf16x8*)&arow[8 * quad];        // k = 0..31
        bf16x8 a1 = *(const bf16x8*)&arow[32 + 8 * quad];   // k = 32..63

        f32x4 acc[4];
        #pragma unroll
        for (int n = 0; n < 4; ++n) acc[n] = (f32x4){0.f, 0.f, 0.f, 0.f};
        #pragma unroll
        for (int n = 0; n < 4; ++n) {
            acc[n] = __builtin_amdgcn_mfma_f32_16x16x32_bf16(a0, bfrag[n][0], acc[n], 0, 0, 0);
            acc[n] = __builtin_amdgcn_mfma_f32_16x16x32_bf16(a1, bfrag[n][1], acc[n], 0, 0, 0);
        }

        // epilogue: +b2, silu, *w3[col], reduce cols (4 N-tiles + 16 lanes)
        float part[4] = {0.f, 0.f, 0.f, 0.f};
        #pragma unroll
        for (int n = 0; n < 4; ++n) {
            #pragma unroll
            for (int r = 0; r < 4; ++r) {
                float v = fast_silu(acc[n][r] + b2c[n]);
                part[r] += v * w3c[n];
            }
        }
        #pragma unroll
        for (int m = 1; m < 16; m <<= 1) {
            #pragma unroll
            for (int r = 0; r < 4; ++r)
                part[r] += __shfl_xor(part[r], m, 16);
        }
        if (l15 == 0) {
            #pragma unroll
            for (int r = 0; r < 4; ++r)
                gs[(quad * 4 + r) * 17 + t] = part[r];
        }
    }
    __syncthreads();

    // ---- combine + diag + mask + store ----
    const int fq = tid >> 4, fk = tid & 15;
    float logit = bils[fq * 17 + fk] + gs[fq * 17 + fk] + b3[0] + bias[0];
    int qi = bq * 16 + fq, ki = bk * 16 + fk;
    if (qi == ki) logit = 0.f;
    if (!(mq[fq] != 0 && mk[fk] != 0)) logit = -1e9f;
    out[((size_t)(bb * 1024 + qi)) * 1024 + ki] = logit;
}

extern "C" void kernel_launch(void* const* d_in, const int* in_sizes, int n_in,
                              void* d_out, int out_size, void* d_ws, size_t ws_size,
                              hipStream_t stream) {
    const float* q      = (const float*)d_in[0];   // [4,1024,256]
    const float* coords = (const float*)d_in[1];   // [4,1024,2]
    const int*   amask  = (const int*)d_in[2];     // [4,1024]
    const float* W      = (const float*)d_in[3];   // [256,256]
    const float* w1     = (const float*)d_in[4];   // [6,64]
    const float* b1     = (const float*)d_in[5];   // [64]
    const float* w2     = (const float*)d_in[6];   // [64,64]
    const float* b2     = (const float*)d_in[7];   // [64]
    const float* w3     = (const float*)d_in[8];   // [64,1]
    const float* b3     = (const float*)d_in[9];   // [1]
    const float* bias   = (const float*)d_in[10];  // [1]
    float* out = (float*)d_out;

    float* qW = (float*)d_ws;  // 4 MB scratch

    qw_gemm_kernel<<<dim3(512), dim3(256), 0, stream>>>(q, W, qW);
    edge_head_kernel<<<dim3(64, 64, 4), dim3(256), 0, stream>>>(
        qW, q, coords, amask, w1, b1, w2, b2, w3, b3, bias, out);
}

// Round 3
// 198.991 us; speedup vs baseline: 2.8453x; 1.7425x over previous
//
#include <hip/hip_runtime.h>

typedef float f32x2 __attribute__((ext_vector_type(2)));
typedef float f32x4 __attribute__((ext_vector_type(4)));
typedef __bf16 bf16x8 __attribute__((ext_vector_type(8)));

#define HS0 0.25f
#define HS1 0.5f

__device__ __forceinline__ unsigned short f2bf(float f) {
    union { float f; unsigned u; } v; v.f = f;
    return (unsigned short)((v.u + 0x8000u) >> 16);
}

// hard-sigmoid silu on a packed f32x2: x * clamp(0.25x+0.5, 0, 1)
__device__ __forceinline__ f32x2 hsilu2(f32x2 x) {
    f32x2 t = __builtin_elementwise_fma(x, (f32x2){HS0, HS0}, (f32x2){HS1, HS1});
    t = __builtin_elementwise_max(t, (f32x2){0.f, 0.f});
    t = __builtin_elementwise_min(t, (f32x2){1.f, 1.f});
    return x * t;
}

// ---------------------------------------------------------------------------
// Kernel 0: pack w2 (64x64 f32) into fp8 e4m3 MFMA-B-fragment order.
// w2f[f*64 + lane] (8 bytes) = w2[32*s + 8*q + j][16*n + l15], f = s*4 + n.
// ---------------------------------------------------------------------------
__global__ __launch_bounds__(256) void prep_w2_kernel(
    const float* __restrict__ w2, long long* __restrict__ w2f)
{
    int t = blockIdx.x * 256 + threadIdx.x;   // 0..511
    if (t >= 512) return;
    int f = t >> 6, lane = t & 63;
    int q8 = (lane >> 4) * 8;
    int col = (f & 3) * 16 + (lane & 15);
    int s = f >> 2;
    int d[2];
    #pragma unroll
    for (int h = 0; h < 2; ++h) {
        float v0 = w2[(32 * s + q8 + 4 * h + 0) * 64 + col];
        float v1 = w2[(32 * s + q8 + 4 * h + 1) * 64 + col];
        float v2 = w2[(32 * s + q8 + 4 * h + 2) * 64 + col];
        float v3 = w2[(32 * s + q8 + 4 * h + 3) * 64 + col];
        int lo = __builtin_amdgcn_cvt_pk_fp8_f32(v0, v1, 0, false);
        d[h]   = __builtin_amdgcn_cvt_pk_fp8_f32(v2, v3, lo, true);
    }
    long long packed;
    __builtin_memcpy(&packed, d, 8);
    w2f[t] = packed;
}

// ---------------------------------------------------------------------------
// Kernel 1: qW = q @ W -> bf16; also emit q as bf16.
// ---------------------------------------------------------------------------
__global__ __launch_bounds__(256) void qw_gemm_kernel(
    const float* __restrict__ q, const float* __restrict__ W,
    unsigned short* __restrict__ qWb16, unsigned short* __restrict__ qb16)
{
    __shared__ float qs[8 * 256];
    const int tid = threadIdx.x;
    const int rowBase = blockIdx.x * 8;
    const float* qb = q + (size_t)rowBase * 256;

    for (int s = tid; s < 8 * 64; s += 256)
        ((float4*)qs)[s] = ((const float4*)qb)[s];
    __syncthreads();

    // emit q rows as bf16 while they're hot
    for (int s = tid; s < 512; s += 256) {
        float4 v = ((const float4*)qs)[s];
        ushort4 u = make_ushort4(f2bf(v.x), f2bf(v.y), f2bf(v.z), f2bf(v.w));
        ((ushort4*)qb16)[(size_t)rowBase * 64 + s] = u;
    }

    float acc[8] = {0.f, 0.f, 0.f, 0.f, 0.f, 0.f, 0.f, 0.f};
    for (int k = 0; k < 256; k += 4) {
        float w0 = W[(k + 0) * 256 + tid];
        float w1v = W[(k + 1) * 256 + tid];
        float w2v = W[(k + 2) * 256 + tid];
        float w3v = W[(k + 3) * 256 + tid];
        #pragma unroll
        for (int r = 0; r < 8; ++r) {
            float4 qv = *(const float4*)&qs[r * 256 + k];
            acc[r] += qv.x * w0 + qv.y * w1v + qv.z * w2v + qv.w * w3v;
        }
    }
    for (int r = 0; r < 8; ++r)
        qWb16[(size_t)(rowBase + r) * 256 + tid] = f2bf(acc[r]);
}

// ---------------------------------------------------------------------------
// Kernel 2: fused bilinear(bf16 MFMA) + geo-MLP(layer1 pk-fp32, layer2 fp8
// MFMA) + mask. Block = 256 threads = one 16x16 pair tile.
// LDS layout:
//  qWs/qks: 16 rows x 512B bf16, 16B-chunk XOR swizzle c^=(row&7) (no pad)
//  h1s: 256 rows x 72B fp8 (64B data + 8B pad; stride 72B = 18 dwords)
// ---------------------------------------------------------------------------
__global__ __launch_bounds__(256, 4) void edge_head_kernel(
    const unsigned short* __restrict__ qWb16, const unsigned short* __restrict__ qb16,
    const long long* __restrict__ w2f,
    const float* __restrict__ coords, const int* __restrict__ amask,
    const float* __restrict__ w1, const float* __restrict__ b1,
    const float* __restrict__ b2,
    const float* __restrict__ w3, const float* __restrict__ b3,
    const float* __restrict__ bias, float* __restrict__ out)
{
    __shared__ unsigned char qWs[16 * 512];
    __shared__ unsigned char qks[16 * 512];
    __shared__ unsigned char h1s[256 * 72];
    __shared__ float bilp[4 * 256];   // per-wave bilinear partials [w][row][col]
    __shared__ float gs[256];         // geo logits [row=ql][col=kl]

    const int tid  = threadIdx.x;
    const int lane = tid & 63;
    const int wv   = tid >> 6;
    const int l15  = lane & 15;
    const int quad = lane >> 4;
    const int bk = blockIdx.x, bq = blockIdx.y, bb = blockIdx.z;

    // ---- w2 fp8 B-fragments + b2/w3 columns ----
    long long bfrag[8];
    float b2c[4], w3c[4];
    #pragma unroll
    for (int f = 0; f < 8; ++f) bfrag[f] = w2f[f * 64 + lane];
    #pragma unroll
    for (int n = 0; n < 4; ++n) { b2c[n] = b2[16 * n + l15]; w3c[n] = w3[16 * n + l15]; }

    // ---- stage qW / q tiles (bf16, swizzled) ----
    {
        const ushort4* qWg = (const ushort4*)qWb16 + (size_t)(bb * 1024 + bq * 16) * 64;
        const ushort4* qkg = (const ushort4*)qb16  + (size_t)(bb * 1024 + bk * 16) * 64;
        #pragma unroll
        for (int it = 0; it < 4; ++it) {
            int s = tid + it * 256;          // ushort4 index, 0..1023
            int row = s >> 6, c4 = s & 63;
            int off = row * 512 + (((c4 >> 1) ^ (row & 7)) << 4) + ((c4 & 1) << 3);
            *(ushort4*)(qWs + off) = qWg[s];
            *(ushort4*)(qks + off) = qkg[s];
        }
    }

    // ---- features + layer1 (pk-fp32) + hard-silu -> h1s (fp8) ----
    {
        const int ql = tid & 15, kl = tid >> 4;
        int qg = bb * 1024 + bq * 16 + ql;
        int kg = bb * 1024 + bk * 16 + kl;
        float2 cq = *(const float2*)&coords[qg * 2];
        float2 ck = *(const float2*)&coords[kg * 2];
        float dx = cq.x - ck.x, dy = cq.y - ck.y;
        float dist2 = dx * dx + dy * dy;
        float dist = sqrtf(dist2 + 1e-8f);
        bool mz = (fabsf(dx) < 1e-6f) && (fabsf(dy) < 1e-6f);
        float dxs = mz ? 1e-6f : dx;
        float dys = mz ? 1e-6f : dy;
        float rinv = __builtin_amdgcn_rsqf(dxs * dxs + dys * dys);
        float sv = dys * rinv, cv = dxs * rinv;

        f32x2 fdx = {dx, dx}, fdy = {dy, dy}, fds = {dist, dist},
              fd2 = {dist2, dist2}, fsv = {sv, sv}, fcv = {cv, cv};
        unsigned hbase = tid * 72;
        #pragma unroll
        for (int g = 0; g < 4; ++g) {       // 16 h-values per group -> 16B
            int dwords[4];
            #pragma unroll
            for (int d = 0; d < 2; ++d) {   // 2 dword-pairs
                int i = g * 16 + d * 8;
                f32x2 hA = {b1[i], b1[i + 1]};
                f32x2 hB = {b1[i + 2], b1[i + 3]};
                f32x2 hC = {b1[i + 4], b1[i + 5]};
                f32x2 hD = {b1[i + 6], b1[i + 7]};
                hA = __builtin_elementwise_fma(fdx, *(const f32x2*)&w1[i], hA);
                hB = __builtin_elementwise_fma(fdx, *(const f32x2*)&w1[i + 2], hB);
                hC = __builtin_elementwise_fma(fdx, *(const f32x2*)&w1[i + 4], hC);
                hD = __builtin_elementwise_fma(fdx, *(const f32x2*)&w1[i + 6], hD);
                hA = __builtin_elementwise_fma(fdy, *(const f32x2*)&w1[64 + i], hA);
                hB = __builtin_elementwise_fma(fdy, *(const f32x2*)&w1[66 + i], hB);
                hC = __builtin_elementwise_fma(fdy, *(const f32x2*)&w1[68 + i], hC);
                hD = __builtin_elementwise_fma(fdy, *(const f32x2*)&w1[70 + i], hD);
                hA = __builtin_elementwise_fma(fds, *(const f32x2*)&w1[128 + i], hA);
                hB = __builtin_elementwise_fma(fds, *(const f32x2*)&w1[130 + i], hB);
                hC = __builtin_elementwise_fma(fds, *(const f32x2*)&w1[132 + i], hC);
                hD = __builtin_elementwise_fma(fds, *(const f32x2*)&w1[134 + i], hD);
                hA = __builtin_elementwise_fma(fd2, *(const f32x2*)&w1[192 + i], hA);
                hB = __builtin_elementwise_fma(fd2, *(const f32x2*)&w1[194 + i], hB);
                hC = __builtin_elementwise_fma(fd2, *(const f32x2*)&w1[196 + i], hC);
                hD = __builtin_elementwise_fma(fd2, *(const f32x2*)&w1[198 + i], hD);
                hA = __builtin_elementwise_fma(fsv, *(const f32x2*)&w1[256 + i], hA);
                hB = __builtin_elementwise_fma(fsv, *(const f32x2*)&w1[258 + i], hB);
                hC = __builtin_elementwise_fma(fsv, *(const f32x2*)&w1[260 + i], hC);
                hD = __builtin_elementwise_fma(fsv, *(const f32x2*)&w1[262 + i], hD);
                hA = __builtin_elementwise_fma(fcv, *(const f32x2*)&w1[320 + i], hA);
                hB = __builtin_elementwise_fma(fcv, *(const f32x2*)&w1[322 + i], hB);
                hC = __builtin_elementwise_fma(fcv, *(const f32x2*)&w1[324 + i], hC);
                hD = __builtin_elementwise_fma(fcv, *(const f32x2*)&w1[326 + i], hD);
                f32x2 sA = hsilu2(hA), sB = hsilu2(hB);
                f32x2 sC = hsilu2(hC), sD = hsilu2(hD);
                int lo0 = __builtin_amdgcn_cvt_pk_fp8_f32(sA.x, sA.y, 0, false);
                dwords[d * 2 + 0] = __builtin_amdgcn_cvt_pk_fp8_f32(sB.x, sB.y, lo0, true);
                int lo1 = __builtin_amdgcn_cvt_pk_fp8_f32(sC.x, sC.y, 0, false);
                dwords[d * 2 + 1] = __builtin_amdgcn_cvt_pk_fp8_f32(sD.x, sD.y, lo1, true);
            }
            *(int2*)(h1s + hbase + g * 16)     = make_int2(dwords[0], dwords[1]);
            *(int2*)(h1s + hbase + g * 16 + 8) = make_int2(dwords[2], dwords[3]);
        }
    }
    __syncthreads();

    // ---- bilinear partial (each wave: 2 of 8 K-steps) ----
    {
        f32x4 accb = {0.f, 0.f, 0.f, 0.f};
        #pragma unroll
        for (int i = 0; i < 2; ++i) {
            int s = 2 * wv + i;
            int off = l15 * 512 + ((((s << 2) + quad) ^ (l15 & 7)) << 4);
            bf16x8 a = *(const bf16x8*)(qWs + off);
            bf16x8 b = *(const bf16x8*)(qks + off);
            accb = __builtin_amdgcn_mfma_f32_16x16x32_bf16(a, b, accb, 0, 0, 0);
        }
        #pragma unroll
        for (int r = 0; r < 4; ++r)
            bilp[wv * 256 + (quad * 4 + r) * 16 + l15] = accb[r];
    }

    // ---- layer2 via fp8 MFMA: each wave owns 4 M-tiles ----
    #pragma unroll
    for (int tt = 0; tt < 4; ++tt) {
        int t = wv * 4 + tt;
        unsigned rbase = (unsigned)(t * 16 + l15) * 72 + 8 * quad;
        long long a0 = *(const long long*)(h1s + rbase);
        long long a1 = *(const long long*)(h1s + rbase + 32);

        f32x4 acc[4];
        #pragma unroll
        for (int n = 0; n < 4; ++n)
            acc[n] = (f32x4){b2c[n], b2c[n], b2c[n], b2c[n]};   // fold b2
        #pragma unroll
        for (int n = 0; n < 4; ++n) {
            acc[n] = __builtin_amdgcn_mfma_f32_16x16x32_fp8_fp8(a0, bfrag[n * 2 + 0], acc[n], 0, 0, 0);
            acc[n] = __builtin_amdgcn_mfma_f32_16x16x32_fp8_fp8(a1, bfrag[n * 2 + 1], acc[n], 0, 0, 0);
        }

        // epilogue: silu, *w3, reduce over the 16 cols held by l15 lanes
        f32x2 p0 = {0.f, 0.f}, p1 = {0.f, 0.f};
        #pragma unroll
        for (int n = 0; n < 4; ++n) {
            f32x2 w3n = {w3c[n], w3c[n]};
            f32x2 x0 = {acc[n][0], acc[n][1]};
            f32x2 x1 = {acc[n][2], acc[n][3]};
            p0 = __builtin_elementwise_fma(hsilu2(x0), w3n, p0);
            p1 = __builtin_elementwise_fma(hsilu2(x1), w3n, p1);
        }
        // 16-lane xor reduction on the DS pipe
        #define SWZ_STEP(pat)                                                              \
            p0.x += __builtin_bit_cast(float, __builtin_amdgcn_ds_swizzle(__builtin_bit_cast(int, p0.x), pat)); \
            p0.y += __builtin_bit_cast(float, __builtin_amdgcn_ds_swizzle(__builtin_bit_cast(int, p0.y), pat)); \
            p1.x += __builtin_bit_cast(float, __builtin_amdgcn_ds_swizzle(__builtin_bit_cast(int, p1.x), pat)); \
            p1.y += __builtin_bit_cast(float, __builtin_amdgcn_ds_swizzle(__builtin_bit_cast(int, p1.y), pat));
        SWZ_STEP(0x041F)
        SWZ_STEP(0x081F)
        SWZ_STEP(0x101F)
        SWZ_STEP(0x201F)
        #undef SWZ_STEP

        if (l15 < 4) {
            f32x2 pv = (l15 & 2) ? p1 : p0;
            float val = (l15 & 1) ? pv.y : pv.x;
            gs[(quad * 4 + l15) * 16 + t] = val;   // [row=ql][col=kl]
        }
    }
    __syncthreads();

    // ---- combine + diag + mask + store ----
    const int fq = tid >> 4, fk = tid & 15;
    float logit = bilp[0 * 256 + fq * 16 + fk] + bilp[1 * 256 + fq * 16 + fk]
                + bilp[2 * 256 + fq * 16 + fk] + bilp[3 * 256 + fq * 16 + fk]
                + gs[fq * 16 + fk] + b3[0] + bias[0];
    int qi = bq * 16 + fq, ki = bk * 16 + fk;
    int mqv = amask[bb * 1024 + qi], mkv = amask[bb * 1024 + ki];
    if (qi == ki) logit = 0.f;
    if (!(mqv != 0 && mkv != 0)) logit = -1e9f;
    out[((size_t)(bb * 1024 + qi)) * 1024 + ki] = logit;
}

extern "C" void kernel_launch(void* const* d_in, const int* in_sizes, int n_in,
                              void* d_out, int out_size, void* d_ws, size_t ws_size,
                              hipStream_t stream) {
    const float* q      = (const float*)d_in[0];   // [4,1024,256]
    const float* coords = (const float*)d_in[1];   // [4,1024,2]
    const int*   amask  = (const int*)d_in[2];     // [4,1024]
    const float* W      = (const float*)d_in[3];   // [256,256]
    const float* w1     = (const float*)d_in[4];   // [6,64]
    const float* b1     = (const float*)d_in[5];   // [64]
    const float* w2     = (const float*)d_in[6];   // [64,64]
    const float* b2     = (const float*)d_in[7];   // [64]
    const float* w3     = (const float*)d_in[8];   // [64,1]
    const float* b3     = (const float*)d_in[9];   // [1]
    const float* bias   = (const float*)d_in[10];  // [1]
    float* out = (float*)d_out;

    unsigned short* qWb16 = (unsigned short*)d_ws;                 // 2 MB
    unsigned short* qb16  = qWb16 + 4096 * 256;                    // 2 MB
    long long*      w2f   = (long long*)(qb16 + 4096 * 256);       // 4 KB

    prep_w2_kernel<<<dim3(2), dim3(256), 0, stream>>>(w2, w2f);
    qw_gemm_kernel<<<dim3(512), dim3(256), 0, stream>>>(q, W, qWb16, qb16);
    edge_head_kernel<<<dim3(64, 64, 4), dim3(256), 0, stream>>>(
        qWb16, qb16, w2f, coords, amask, w1, b1, b2, w3, b3, bias, out);
}

// Round 4
// 165.366 us; speedup vs baseline: 3.4239x; 1.2033x over previous
//
#include <hip/hip_runtime.h>

typedef float f32x2 __attribute__((ext_vector_type(2)));
typedef float f32x4 __attribute__((ext_vector_type(4)));
typedef __bf16 bf16x8 __attribute__((ext_vector_type(8)));

__device__ __forceinline__ unsigned short f2bf(float f) {
    union { float f; unsigned u; } v; v.f = f;
    return (unsigned short)((v.u + 0x8000u) >> 16);
}

// hard-sigmoid silu on packed f32x2: x * med3(0.25x+0.5, 0, 1)
__device__ __forceinline__ f32x2 hsilu2(f32x2 x) {
    f32x2 t = __builtin_elementwise_fma(x, (f32x2){0.25f, 0.25f}, (f32x2){0.5f, 0.5f});
    t.x = __builtin_amdgcn_fmed3f(t.x, 0.f, 1.f);
    t.y = __builtin_amdgcn_fmed3f(t.y, 0.f, 1.f);
    return x * t;
}

// ---------------------------------------------------------------------------
// Kernel 0 (prep): blocks 0..4095 fill out with -1e9; blocks 4096..4127 pack
// W into bf16 MFMA-B fragments (Wf); 4128..4129 pack w2 into fp8 B-frags;
// 4130..4133 compact per-batch active indices (qlist, Na).
// ---------------------------------------------------------------------------
__global__ __launch_bounds__(256) void prep_kernel(
    const float* __restrict__ W, const float* __restrict__ w2,
    const int* __restrict__ amask,
    float* __restrict__ out, unsigned short* __restrict__ Wf,
    long long* __restrict__ w2f, int* __restrict__ qlist, int* __restrict__ Na)
{
    const int blk = blockIdx.x, tid = threadIdx.x;

    if (blk < 4096) {                       // ---- fill out = -1e9 ----
        ((float4*)out)[blk * 256 + tid] = make_float4(-1e9f, -1e9f, -1e9f, -1e9f);
        return;
    }
    if (blk < 4128) {                       // ---- pack W -> bf16 B-frags ----
        int t = (blk - 4096) * 256 + tid;   // 0..8191 = (nt*8+s)*64 + lane
        int f = t >> 6, lane = t & 63;
        int nt = f >> 3, s = f & 7;
        int quad = lane >> 4, l15 = lane & 15;
        unsigned short u[8];
        #pragma unroll
        for (int j = 0; j < 8; ++j)
            u[j] = f2bf(W[(32 * s + 8 * quad + j) * 256 + 16 * nt + l15]);
        *(uint4*)(Wf + t * 8) = *(const uint4*)u;
        return;
    }
    if (blk < 4130) {                       // ---- pack w2 -> fp8 B-frags ----
        int t = (blk - 4128) * 256 + tid;   // 0..511
        int f = t >> 6, lane = t & 63;
        int q8 = (lane >> 4) * 8;
        int col = (f & 3) * 16 + (lane & 15);
        int s = f >> 2;
        int d[2];
        #pragma unroll
        for (int h = 0; h < 2; ++h) {
            float v0 = w2[(32 * s + q8 + 4 * h + 0) * 64 + col];
            float v1 = w2[(32 * s + q8 + 4 * h + 1) * 64 + col];
            float v2 = w2[(32 * s + q8 + 4 * h + 2) * 64 + col];
            float v3 = w2[(32 * s + q8 + 4 * h + 3) * 64 + col];
            int lo = __builtin_amdgcn_cvt_pk_fp8_f32(v0, v1, 0, false);
            d[h]   = __builtin_amdgcn_cvt_pk_fp8_f32(v2, v3, lo, true);
        }
        long long packed; __builtin_memcpy(&packed, d, 8);
        w2f[t] = packed;
        return;
    }
    // ---- compaction: batch b, 256 threads x 4 indices, stable order ----
    {
        __shared__ int ssum[256];
        int b = blk - 4130;
        const int* am = amask + b * 1024;
        int base = tid * 4;
        int m0 = am[base + 0] != 0, m1 = am[base + 1] != 0,
            m2 = am[base + 2] != 0, m3 = am[base + 3] != 0;
        int c = m0 + m1 + m2 + m3;
        ssum[tid] = c;
        __syncthreads();
        for (int off = 1; off < 256; off <<= 1) {
            int v = (tid >= off) ? ssum[tid - off] : 0;
            __syncthreads();
            ssum[tid] += v;
            __syncthreads();
        }
        int pos = ssum[tid] - c;
        int* ql = qlist + b * 1024;
        if (m0) ql[pos++] = base + 0;
        if (m1) ql[pos++] = base + 1;
        if (m2) ql[pos++] = base + 2;
        if (m3) ql[pos++] = base + 3;
        if (tid == 255) Na[b] = ssum[255];
    }
}

// ---------------------------------------------------------------------------
// Kernel 1: qW = q @ W via bf16 MFMA. 256 blocks x 256 thr; block = 16 rows x
// 256 cols. Also emits q as bf16 (qb16). Wf holds W in B-frag order.
// ---------------------------------------------------------------------------
__global__ __launch_bounds__(256) void qw_mfma_kernel(
    const float* __restrict__ q, const unsigned short* __restrict__ Wf,
    unsigned short* __restrict__ qWb16, unsigned short* __restrict__ qb16)
{
    __shared__ unsigned char qs[16 * 512];
    const int tid = threadIdx.x;
    const int lane = tid & 63, wv = tid >> 6;
    const int l15 = lane & 15, quad = lane >> 4;
    const int rb = blockIdx.x;

    const float4* qg = (const float4*)(q + (size_t)rb * 16 * 256);
    #pragma unroll
    for (int it = 0; it < 4; ++it) {
        int c = tid + it * 256;            // 8B chunk id: row*64 + c64
        int row = c >> 6, c64 = c & 63;
        float4 v = qg[row * 64 + c64];
        ushort4 u = make_ushort4(f2bf(v.x), f2bf(v.y), f2bf(v.z), f2bf(v.w));
        int off = row * 512 + (((c64 >> 1) ^ (row & 7)) << 4) + ((c64 & 1) << 3);
        *(ushort4*)(qs + off) = u;
        ((ushort4*)qb16)[(size_t)rb * 1024 + row * 64 + c64] = u;
    }
    __syncthreads();

    bf16x8 a[8];
    #pragma unroll
    for (int s = 0; s < 8; ++s)
        a[s] = *(const bf16x8*)(qs + l15 * 512 + ((((s << 2) + quad) ^ (l15 & 7)) << 4));

    f32x4 acc[4];
    #pragma unroll
    for (int n = 0; n < 4; ++n) acc[n] = (f32x4){0.f, 0.f, 0.f, 0.f};

    const uint4* wf = (const uint4*)Wf;
    #pragma unroll
    for (int s = 0; s < 8; ++s) {
        #pragma unroll
        for (int n = 0; n < 4; ++n) {
            int nt = wv * 4 + n;
            uint4 braw = wf[(nt * 8 + s) * 64 + lane];
            bf16x8 bfr = __builtin_bit_cast(bf16x8, braw);
            acc[n] = __builtin_amdgcn_mfma_f32_16x16x32_bf16(a[s], bfr, acc[n], 0, 0, 0);
        }
    }
    #pragma unroll
    for (int n = 0; n < 4; ++n) {
        #pragma unroll
        for (int r = 0; r < 4; ++r) {
            int row = rb * 16 + quad * 4 + r;
            int col = (wv * 4 + n) * 16 + l15;
            qWb16[(size_t)row * 256 + col] = f2bf(acc[n][r]);
        }
    }
}

// ---------------------------------------------------------------------------
// Kernel 2: fused edge head over the COMPACTED active domain.
// Grid 64x64x4; blocks beyond ceil(Na/16) tiles exit. Results scattered by
// real indices; inactive pairs already hold -1e9 from prep fill.
// ---------------------------------------------------------------------------
__global__ __launch_bounds__(256, 4) void edge_head_kernel(
    const unsigned short* __restrict__ qWb16, const unsigned short* __restrict__ qb16,
    const long long* __restrict__ w2f,
    const float* __restrict__ coords,
    const int* __restrict__ qlist, const int* __restrict__ Na,
    const float* __restrict__ w1, const float* __restrict__ b1,
    const float* __restrict__ b2,
    const float* __restrict__ w3, const float* __restrict__ b3,
    const float* __restrict__ bias, float* __restrict__ out)
{
    const int bk = blockIdx.x, bq = blockIdx.y, bb = blockIdx.z;
    const int nb = Na[bb];
    if (bq * 16 >= nb || bk * 16 >= nb) return;

    __shared__ unsigned char qWs[16 * 512];
    __shared__ unsigned char qks[16 * 512];
    __shared__ unsigned char h1s[256 * 72];
    __shared__ float bilp[4 * 256];
    __shared__ float gs[256];

    const int tid  = threadIdx.x;
    const int lane = tid & 63;
    const int wv   = tid >> 6;
    const int l15  = lane & 15;
    const int quad = lane >> 4;
    const int* ql = qlist + bb * 1024;

    // ---- w2 fp8 B-fragments + b2/w3 columns ----
    long long bfrag[8];
    float b2c[4], w3c[4];
    #pragma unroll
    for (int f = 0; f < 8; ++f) bfrag[f] = w2f[f * 64 + lane];
    #pragma unroll
    for (int n = 0; n < 4; ++n) { b2c[n] = b2[16 * n + l15]; w3c[n] = w3[16 * n + l15]; }

    // ---- stage gathered qW / q rows (bf16, swizzled) ----
    {
        const ushort4* qWg = (const ushort4*)qWb16;
        const ushort4* qkg = (const ushort4*)qb16;
        #pragma unroll
        for (int it = 0; it < 4; ++it) {
            int s = tid + it * 256;          // 8B chunk: row*64 + c64
            int row = s >> 6, c64 = s & 63;
            int qi_ = ql[min(bq * 16 + row, nb - 1)];
            int ki_ = ql[min(bk * 16 + row, nb - 1)];
            ushort4 ua = qWg[(size_t)(bb * 1024 + qi_) * 64 + c64];
            ushort4 ub = qkg[(size_t)(bb * 1024 + ki_) * 64 + c64];
            int off = row * 512 + (((c64 >> 1) ^ (row & 7)) << 4) + ((c64 & 1) << 3);
            *(ushort4*)(qWs + off) = ua;
            *(ushort4*)(qks + off) = ub;
        }
    }

    // ---- features + layer1 (pk-fp32) + hard-silu -> h1s (fp8) ----
    {
        const int ql_ = tid & 15, kl_ = tid >> 4;
        int qi = ql[min(bq * 16 + ql_, nb - 1)];
        int ki = ql[min(bk * 16 + kl_, nb - 1)];
        float2 cq = *(const float2*)&coords[(bb * 1024 + qi) * 2];
        float2 ck = *(const float2*)&coords[(bb * 1024 + ki) * 2];
        float dx = cq.x - ck.x, dy = cq.y - ck.y;
        float dist2 = dx * dx + dy * dy;
        float dist = sqrtf(dist2 + 1e-8f);
        bool mz = (fabsf(dx) < 1e-6f) && (fabsf(dy) < 1e-6f);
        float dxs = mz ? 1e-6f : dx;
        float dys = mz ? 1e-6f : dy;
        float rinv = __builtin_amdgcn_rsqf(dxs * dxs + dys * dys);
        float sv = dys * rinv, cv = dxs * rinv;

        f32x2 fdx = {dx, dx}, fdy = {dy, dy}, fds = {dist, dist},
              fd2 = {dist2, dist2}, fsv = {sv, sv}, fcv = {cv, cv};
        unsigned hbase = tid * 72;
        #pragma unroll
        for (int g = 0; g < 4; ++g) {
            int dwords[4];
            #pragma unroll
            for (int d = 0; d < 2; ++d) {
                int i = g * 16 + d * 8;
                f32x2 hA = {b1[i], b1[i + 1]};
                f32x2 hB = {b1[i + 2], b1[i + 3]};
                f32x2 hC = {b1[i + 4], b1[i + 5]};
                f32x2 hD = {b1[i + 6], b1[i + 7]};
                hA = __builtin_elementwise_fma(fdx, *(const f32x2*)&w1[i], hA);
                hB = __builtin_elementwise_fma(fdx, *(const f32x2*)&w1[i + 2], hB);
                hC = __builtin_elementwise_fma(fdx, *(const f32x2*)&w1[i + 4], hC);
                hD = __builtin_elementwise_fma(fdx, *(const f32x2*)&w1[i + 6], hD);
                hA = __builtin_elementwise_fma(fdy, *(const f32x2*)&w1[64 + i], hA);
                hB = __builtin_elementwise_fma(fdy, *(const f32x2*)&w1[66 + i], hB);
                hC = __builtin_elementwise_fma(fdy, *(const f32x2*)&w1[68 + i], hC);
                hD = __builtin_elementwise_fma(fdy, *(const f32x2*)&w1[70 + i], hD);
                hA = __builtin_elementwise_fma(fds, *(const f32x2*)&w1[128 + i], hA);
                hB = __builtin_elementwise_fma(fds, *(const f32x2*)&w1[130 + i], hB);
                hC = __builtin_elementwise_fma(fds, *(const f32x2*)&w1[132 + i], hC);
                hD = __builtin_elementwise_fma(fds, *(const f32x2*)&w1[134 + i], hD);
                hA = __builtin_elementwise_fma(fd2, *(const f32x2*)&w1[192 + i], hA);
                hB = __builtin_elementwise_fma(fd2, *(const f32x2*)&w1[194 + i], hB);
                hC = __builtin_elementwise_fma(fd2, *(const f32x2*)&w1[196 + i], hC);
                hD = __builtin_elementwise_fma(fd2, *(const f32x2*)&w1[198 + i], hD);
                hA = __builtin_elementwise_fma(fsv, *(const f32x2*)&w1[256 + i], hA);
                hB = __builtin_elementwise_fma(fsv, *(const f32x2*)&w1[258 + i], hB);
                hC = __builtin_elementwise_fma(fsv, *(const f32x2*)&w1[260 + i], hC);
                hD = __builtin_elementwise_fma(fsv, *(const f32x2*)&w1[262 + i], hD);
                hA = __builtin_elementwise_fma(fcv, *(const f32x2*)&w1[320 + i], hA);
                hB = __builtin_elementwise_fma(fcv, *(const f32x2*)&w1[322 + i], hB);
                hC = __builtin_elementwise_fma(fcv, *(const f32x2*)&w1[324 + i], hC);
                hD = __builtin_elementwise_fma(fcv, *(const f32x2*)&w1[326 + i], hD);
                f32x2 sA = hsilu2(hA), sB = hsilu2(hB);
                f32x2 sC = hsilu2(hC), sD = hsilu2(hD);
                int lo0 = __builtin_amdgcn_cvt_pk_fp8_f32(sA.x, sA.y, 0, false);
                dwords[d * 2 + 0] = __builtin_amdgcn_cvt_pk_fp8_f32(sB.x, sB.y, lo0, true);
                int lo1 = __builtin_amdgcn_cvt_pk_fp8_f32(sC.x, sC.y, 0, false);
                dwords[d * 2 + 1] = __builtin_amdgcn_cvt_pk_fp8_f32(sD.x, sD.y, lo1, true);
            }
            *(int2*)(h1s + hbase + g * 16)     = make_int2(dwords[0], dwords[1]);
            *(int2*)(h1s + hbase + g * 16 + 8) = make_int2(dwords[2], dwords[3]);
        }
    }
    __syncthreads();

    // ---- bilinear partial (each wave: 2 of 8 K-steps) ----
    {
        f32x4 accb = {0.f, 0.f, 0.f, 0.f};
        #pragma unroll
        for (int i = 0; i < 2; ++i) {
            int s = 2 * wv + i;
            int off = l15 * 512 + ((((s << 2) + quad) ^ (l15 & 7)) << 4);
            bf16x8 a = *(const bf16x8*)(qWs + off);
            bf16x8 b = *(const bf16x8*)(qks + off);
            accb = __builtin_amdgcn_mfma_f32_16x16x32_bf16(a, b, accb, 0, 0, 0);
        }
        #pragma unroll
        for (int r = 0; r < 4; ++r)
            bilp[wv * 256 + (quad * 4 + r) * 16 + l15] = accb[r];
    }

    // ---- layer2 via fp8 MFMA: each wave owns 4 M-tiles ----
    #pragma unroll
    for (int tt = 0; tt < 4; ++tt) {
        int t = wv * 4 + tt;
        unsigned rbase = (unsigned)(t * 16 + l15) * 72 + 8 * quad;
        long long a0 = *(const long long*)(h1s + rbase);
        long long a1 = *(const long long*)(h1s + rbase + 32);

        f32x4 acc[4];
        #pragma unroll
        for (int n = 0; n < 4; ++n)
            acc[n] = (f32x4){b2c[n], b2c[n], b2c[n], b2c[n]};
        #pragma unroll
        for (int n = 0; n < 4; ++n) {
            acc[n] = __builtin_amdgcn_mfma_f32_16x16x32_fp8_fp8(a0, bfrag[n * 2 + 0], acc[n], 0, 0, 0);
            acc[n] = __builtin_amdgcn_mfma_f32_16x16x32_fp8_fp8(a1, bfrag[n * 2 + 1], acc[n], 0, 0, 0);
        }

        f32x2 p0 = {0.f, 0.f}, p1 = {0.f, 0.f};
        #pragma unroll
        for (int n = 0; n < 4; ++n) {
            f32x2 w3n = {w3c[n], w3c[n]};
            f32x2 x0 = {acc[n][0], acc[n][1]};
            f32x2 x1 = {acc[n][2], acc[n][3]};
            p0 = __builtin_elementwise_fma(hsilu2(x0), w3n, p0);
            p1 = __builtin_elementwise_fma(hsilu2(x1), w3n, p1);
        }
        #define SWZ_STEP(pat)                                                              \
            p0.x += __builtin_bit_cast(float, __builtin_amdgcn_ds_swizzle(__builtin_bit_cast(int, p0.x), pat)); \
            p0.y += __builtin_bit_cast(float, __builtin_amdgcn_ds_swizzle(__builtin_bit_cast(int, p0.y), pat)); \
            p1.x += __builtin_bit_cast(float, __builtin_amdgcn_ds_swizzle(__builtin_bit_cast(int, p1.x), pat)); \
            p1.y += __builtin_bit_cast(float, __builtin_amdgcn_ds_swizzle(__builtin_bit_cast(int, p1.y), pat));
        SWZ_STEP(0x041F)
        SWZ_STEP(0x081F)
        SWZ_STEP(0x101F)
        SWZ_STEP(0x201F)
        #undef SWZ_STEP

        if (l15 < 4) {
            f32x2 pv = (l15 & 2) ? p1 : p0;
            float val = (l15 & 1) ? pv.y : pv.x;
            gs[(quad * 4 + l15) * 16 + t] = val;
        }
    }
    __syncthreads();

    // ---- combine + diag + scatter-store (compacted -> real indices) ----
    const int fq = tid >> 4, fk = tid & 15;
    bool valid = (bq * 16 + fq < nb) && (bk * 16 + fk < nb);
    int qi = ql[min(bq * 16 + fq, nb - 1)];
    int ki = ql[min(bk * 16 + fk, nb - 1)];
    float logit = bilp[0 * 256 + fq * 16 + fk] + bilp[1 * 256 + fq * 16 + fk]
                + bilp[2 * 256 + fq * 16 + fk] + bilp[3 * 256 + fq * 16 + fk]
                + gs[fq * 16 + fk] + b3[0] + bias[0];
    if (qi == ki) logit = 0.f;
    if (valid) out[((size_t)(bb * 1024 + qi)) * 1024 + ki] = logit;
}

extern "C" void kernel_launch(void* const* d_in, const int* in_sizes, int n_in,
                              void* d_out, int out_size, void* d_ws, size_t ws_size,
                              hipStream_t stream) {
    const float* q      = (const float*)d_in[0];   // [4,1024,256]
    const float* coords = (const float*)d_in[1];   // [4,1024,2]
    const int*   amask  = (const int*)d_in[2];     // [4,1024]
    const float* W      = (const float*)d_in[3];   // [256,256]
    const float* w1     = (const float*)d_in[4];   // [6,64]
    const float* b1     = (const float*)d_in[5];   // [64]
    const float* w2     = (const float*)d_in[6];   // [64,64]
    const float* b2     = (const float*)d_in[7];   // [64]
    const float* w3     = (const float*)d_in[8];   // [64,1]
    const float* b3     = (const float*)d_in[9];   // [1]
    const float* bias   = (const float*)d_in[10];  // [1]
    float* out = (float*)d_out;

    unsigned short* qWb16 = (unsigned short*)d_ws;              // 2 MB
    unsigned short* qb16  = qWb16 + 4096 * 256;                 // 2 MB
    unsigned short* Wf    = qb16 + 4096 * 256;                  // 128 KB
    long long*      w2f   = (long long*)(Wf + 65536);           // 4 KB
    int*            qlist = (int*)(w2f + 512);                  // 16 KB
    int*            Na    = qlist + 4096;                       // 16 B

    prep_kernel<<<dim3(4134), dim3(256), 0, stream>>>(
        W, w2, amask, out, Wf, w2f, qlist, Na);
    qw_mfma_kernel<<<dim3(256), dim3(256), 0, stream>>>(q, Wf, qWb16, qb16);
    edge_head_kernel<<<dim3(64, 64, 4), dim3(256), 0, stream>>>(
        qWb16, qb16, w2f, coords, qlist, Na, w1, b1, b2, w3, b3, bias, out);
}

// Round 6
// 130.517 us; speedup vs baseline: 4.3381x; 1.2670x over previous
//
#include <hip/hip_runtime.h>

typedef float f32x4 __attribute__((ext_vector_type(4)));
typedef __bf16 bf16x8 __attribute__((ext_vector_type(8)));

__device__ __forceinline__ unsigned short f2bf(float f) {
    union { float f; unsigned u; } v; v.f = f;
    return (unsigned short)((v.u + 0x8000u) >> 16);
}
// hard-sigmoid silu: x * med3(0.25x+0.5, 0, 1)
__device__ __forceinline__ float hsilu(float x) {
    return x * __builtin_amdgcn_fmed3f(__builtin_fmaf(x, 0.25f, 0.5f), 0.f, 1.f);
}
// sigma-permuted hidden: k-position t holds hidden index 16*(t&3) + (t>>2)
// (h1 rows are written as pos = l15*4 + n, so w2 k-rows must be permuted).
__device__ __forceinline__ int sig_hid(int t) { return 16 * (t & 3) + (t >> 2); }

// ---------------------------------------------------------------------------
// prep: blocks 0..1023 fill out=-1e9; 1024..1055 pack W->bf16 B-frags;
// 1056..1057 pack w2->fp8 B-frags (sigma-permuted k); 1058 packs w1(+b1)
// ->fp8 B-frags; 1059..1062 per-batch compaction (qlc + ccomp + Na).
// ---------------------------------------------------------------------------
__global__ __launch_bounds__(256) void prep_kernel(
    const float* __restrict__ W, const float* __restrict__ w2,
    const float* __restrict__ w1, const float* __restrict__ b1,
    const int* __restrict__ amask, const float* __restrict__ coords,
    float* __restrict__ out, unsigned short* __restrict__ Wf,
    long long* __restrict__ w2f, long long* __restrict__ w1f,
    int* __restrict__ qlc, float2* __restrict__ ccomp, int* __restrict__ Na)
{
    const int blk = blockIdx.x, tid = threadIdx.x;

    if (blk < 1024) {                       // fill out with -1e9
        const float4 v = make_float4(-1e9f, -1e9f, -1e9f, -1e9f);
        float4* o = (float4*)out + blk * 1024;
        o[tid] = v; o[256 + tid] = v; o[512 + tid] = v; o[768 + tid] = v;
        return;
    }
    if (blk < 1056) {                       // W -> bf16 B-frags
        int t = (blk - 1024) * 256 + tid;   // (nt*8+s)*64 + lane, t<8192
        int f = t >> 6, lane = t & 63;
        int nt = f >> 3, s = f & 7;
        int quad = lane >> 4, l15 = lane & 15;
        unsigned short u[8];
        #pragma unroll
        for (int j = 0; j < 8; ++j)
            u[j] = f2bf(W[(32 * s + 8 * quad + j) * 256 + 16 * nt + l15]);
        *(uint4*)(Wf + t * 8) = *(const uint4*)u;
        return;
    }
    if (blk < 1058) {                       // w2 -> fp8 B-frags, f = n2*2+s
        int t = (blk - 1056) * 256 + tid;   // t<512
        int f = t >> 6, lane = t & 63;
        int n2 = f >> 1, s = f & 1;
        int quad = lane >> 4, l15 = lane & 15;
        int d[2];
        #pragma unroll
        for (int h = 0; h < 2; ++h) {
            float v[4];
            #pragma unroll
            for (int e = 0; e < 4; ++e) {
                int tp = 32 * s + 8 * quad + 4 * h + e;
                v[e] = w2[sig_hid(tp) * 64 + 16 * n2 + l15];
            }
            int lo = __builtin_amdgcn_cvt_pk_fp8_f32(v[0], v[1], 0, false);
            d[h]   = __builtin_amdgcn_cvt_pk_fp8_f32(v[2], v[3], lo, true);
        }
        long long pk; __builtin_memcpy(&pk, d, 8);
        w2f[t] = pk;
        return;
    }
    if (blk == 1058) {                      // w1(+b1) -> fp8 B-frags
        int n = tid >> 6, lane = tid & 63;
        int quad = lane >> 4, l15 = lane & 15;
        int col = 16 * n + l15;
        int d[2] = {0, 0};
        if (quad == 0) {                    // only k=0..7 rows are nonzero
            float v0 = w1[0 * 64 + col], v1 = w1[1 * 64 + col];
            float v2 = w1[2 * 64 + col], v3 = w1[3 * 64 + col];
            float v4 = w1[4 * 64 + col], v5 = w1[5 * 64 + col];
            float v6 = b1[col];
            int lo = __builtin_amdgcn_cvt_pk_fp8_f32(v0, v1, 0, false);
            d[0]   = __builtin_amdgcn_cvt_pk_fp8_f32(v2, v3, lo, true);
            int l1 = __builtin_amdgcn_cvt_pk_fp8_f32(v4, v5, 0, false);
            d[1]   = __builtin_amdgcn_cvt_pk_fp8_f32(v6, 0.f, l1, true);
        }
        long long pk; __builtin_memcpy(&pk, d, 8);
        w1f[tid] = pk;
        return;
    }
    // compaction: batch b, stable order, + compacted coords
    {
        __shared__ int ssum[256];
        int b = blk - 1059;
        const int* am = amask + b * 1024;
        const float2* cg = (const float2*)coords + b * 1024;
        int base = tid * 4;
        int m0 = am[base + 0] != 0, m1 = am[base + 1] != 0,
            m2 = am[base + 2] != 0, m3 = am[base + 3] != 0;
        int c = m0 + m1 + m2 + m3;
        ssum[tid] = c;
        __syncthreads();
        for (int off = 1; off < 256; off <<= 1) {
            int v = (tid >= off) ? ssum[tid - off] : 0;
            __syncthreads();
            ssum[tid] += v;
            __syncthreads();
        }
        int pos = ssum[tid] - c;
        int* ql = qlc + b * 1024;
        float2* cc = ccomp + b * 1024;
        if (m0) { ql[pos] = base + 0; cc[pos] = cg[base + 0]; pos++; }
        if (m1) { ql[pos] = base + 1; cc[pos] = cg[base + 1]; pos++; }
        if (m2) { ql[pos] = base + 2; cc[pos] = cg[base + 2]; pos++; }
        if (m3) { ql[pos] = base + 3; cc[pos] = cg[base + 3]; pos++; }
        if (tid == 255) Na[b] = ssum[255];
    }
}

// ---------------------------------------------------------------------------
// qw: compacted qW = q[qlc] @ W via bf16 MFMA; also emits compacted q (bf16).
// ---------------------------------------------------------------------------
__global__ __launch_bounds__(256) void qw_mfma_kernel(
    const float* __restrict__ q, const unsigned short* __restrict__ Wf,
    const int* __restrict__ qlc, const int* __restrict__ Na,
    unsigned short* __restrict__ qWc, unsigned short* __restrict__ qc)
{
    const int bb = blockIdx.y, iq = blockIdx.x;
    const int nb = Na[bb];
    if (iq * 16 >= nb) return;

    __shared__ unsigned char qs[16 * 512];
    const int tid = threadIdx.x;
    const int lane = tid & 63, wv = tid >> 6;
    const int l15 = lane & 15, quad = lane >> 4;

    #pragma unroll
    for (int it = 0; it < 4; ++it) {
        int s = tid + it * 256;
        int row = s >> 6, c64 = s & 63;
        int g = qlc[(bb << 10) + min(iq * 16 + row, nb - 1)];  // clamped gather
        float4 v = ((const float4*)q)[(size_t)((bb << 10) + g) * 64 + c64];
        ushort4 u = make_ushort4(f2bf(v.x), f2bf(v.y), f2bf(v.z), f2bf(v.w));
        int off = row * 512 + (((c64 >> 1) ^ (row & 7)) << 4) + ((c64 & 1) << 3);
        *(ushort4*)(qs + off) = u;
        ((ushort4*)qc)[(size_t)((bb << 10) + iq * 16 + row) * 64 + c64] = u;
    }
    __syncthreads();

    bf16x8 a[8];
    #pragma unroll
    for (int s = 0; s < 8; ++s)
        a[s] = *(const bf16x8*)(qs + l15 * 512 + ((((s << 2) + quad) ^ (l15 & 7)) << 4));

    f32x4 acc[4];
    #pragma unroll
    for (int n = 0; n < 4; ++n) acc[n] = (f32x4){0.f, 0.f, 0.f, 0.f};
    const uint4* wf = (const uint4*)Wf;
    #pragma unroll
    for (int s = 0; s < 8; ++s) {
        #pragma unroll
        for (int n = 0; n < 4; ++n) {
            int nt = wv * 4 + n;
            uint4 braw = wf[(nt * 8 + s) * 64 + lane];
            acc[n] = __builtin_amdgcn_mfma_f32_16x16x32_bf16(
                a[s], __builtin_bit_cast(bf16x8, braw), acc[n], 0, 0, 0);
        }
    }
    #pragma unroll
    for (int n = 0; n < 4; ++n)
        #pragma unroll
        for (int r = 0; r < 4; ++r) {
            int row = iq * 16 + quad * 4 + r;
            int col = (wv * 4 + n) * 16 + l15;
            qWc[(size_t)((bb << 10) + row) * 256 + col] = f2bf(acc[n][r]);
        }
}

// ---------------------------------------------------------------------------
// edge: persistent blocks over the exact compacted tile list.
// Per tile: stage qWc/qc (bf16, XOR-swizzled) + fp8 features (h1s row pad);
// sync; bilinear bf16 MFMA (K split over waves); layer1 fp8 MFMA ->
// silu -> h1 fp8 (sigma-permuted rows); sync (h1 visibility!); layer2 fp8
// MFMA + register epilogue (hsilu, *w3, ds_swizzle 16-lane reduce) -> gs;
// sync; combine + scatter store. Pair index p = kl*16 + ql.
// ---------------------------------------------------------------------------
__global__ __launch_bounds__(256, 4) void edge_head_kernel(
    const unsigned short* __restrict__ qWc, const unsigned short* __restrict__ qc,
    const long long* __restrict__ w2f, const long long* __restrict__ w1f,
    const float2* __restrict__ ccomp,
    const int* __restrict__ qlc, const int* __restrict__ Na,
    const float* __restrict__ b2, const float* __restrict__ w3,
    const float* __restrict__ b3, const float* __restrict__ bias,
    float* __restrict__ out)
{
    __shared__ unsigned char qWs[16 * 512];
    __shared__ unsigned char qks[16 * 512];
    __shared__ __align__(16) unsigned char h1s[256 * 72];  // 64B data + 8B feat pad
    __shared__ float bilp[4 * 272];                        // 4 waves x 16x17
    __shared__ float gs[256];

    const int tid  = threadIdx.x;
    const int lane = tid & 63;
    const int wv   = tid >> 6;
    const int l15  = lane & 15;
    const int quad = lane >> 4;

    // per-block constants
    long long w2frag[8], w1frag[4];
    #pragma unroll
    for (int f = 0; f < 8; ++f) w2frag[f] = w2f[f * 64 + lane];
    #pragma unroll
    for (int n = 0; n < 4; ++n) w1frag[n] = w1f[n * 64 + lane];
    float b2c[4], w3c[4];
    #pragma unroll
    for (int n = 0; n < 4; ++n) { b2c[n] = b2[16 * n + l15]; w3c[n] = w3[16 * n + l15]; }
    const float c0 = b3[0] + bias[0];

    int nt[4], off[5];
    off[0] = 0;
    #pragma unroll
    for (int b = 0; b < 4; ++b) {
        int nb = Na[b];
        nt[b] = (nb + 15) >> 4;
        off[b + 1] = off[b] + nt[b] * nt[b];
    }
    const int T = off[4];

    for (int t = blockIdx.x; t < T; t += gridDim.x) {
        int bb = 0;
        while (bb < 3 && t >= off[bb + 1]) bb++;
        int loc = t - off[bb];
        int ntb = nt[bb];
        int iq = loc / ntb, ik = loc - iq * ntb;
        int nb = Na[bb];

        // ---- stage (16B chunks, XOR-swizzled) + fp8 features ----
        {
            const uint4* qWg = (const uint4*)qWc + (size_t)((bb << 10) + iq * 16) * 32;
            const uint4* qkg = (const uint4*)qc  + (size_t)((bb << 10) + ik * 16) * 32;
            #pragma unroll
            for (int it = 0; it < 2; ++it) {
                int s = tid + it * 256;       // 16B chunk: row*32 + c16
                int row = s >> 5, c16 = s & 31;
                int o = row * 512 + ((c16 ^ (row & 7)) << 4);
                *(uint4*)(qWs + o) = qWg[s];
                *(uint4*)(qks + o) = qkg[s];
            }
            // features for pair p = tid (ql = p&15, kl = p>>4); clamped reads
            int qa = min(iq * 16 + (tid & 15), nb - 1);
            int ka = min(ik * 16 + (tid >> 4), nb - 1);
            float2 cq = ccomp[(bb << 10) + qa];
            float2 ck = ccomp[(bb << 10) + ka];
            float dx = cq.x - ck.x, dy = cq.y - ck.y;
            float dist2 = dx * dx + dy * dy;
            float dist = sqrtf(dist2 + 1e-8f);
            bool mz = (fabsf(dx) < 1e-6f) && (fabsf(dy) < 1e-6f);
            float dxs = mz ? 1e-6f : dx;
            float dys = mz ? 1e-6f : dy;
            float rinv = __builtin_amdgcn_rsqf(dxs * dxs + dys * dys);
            float sv = dys * rinv, cv = dxs * rinv;
            int a  = __builtin_amdgcn_cvt_pk_fp8_f32(dx, dy, 0, false);
            int d0 = __builtin_amdgcn_cvt_pk_fp8_f32(dist, dist2, a, true);
            int b  = __builtin_amdgcn_cvt_pk_fp8_f32(sv, cv, 0, false);
            int d1 = b | 0x00380000;          // bytes [sv, cv, 1.0fp8, 0]
            *(int2*)(h1s + tid * 72 + 64) = make_int2(d0, d1);
        }
        __syncthreads();

        // ---- bilinear: wave wv does K-steps 2wv, 2wv+1 ----
        {
            f32x4 accb = {0.f, 0.f, 0.f, 0.f};
            #pragma unroll
            for (int i = 0; i < 2; ++i) {
                int s = 2 * wv + i;
                int o = l15 * 512 + ((((s << 2) + quad) ^ (l15 & 7)) << 4);
                bf16x8 av = *(const bf16x8*)(qWs + o);
                bf16x8 bv = *(const bf16x8*)(qks + o);
                accb = __builtin_amdgcn_mfma_f32_16x16x32_bf16(av, bv, accb, 0, 0, 0);
            }
            #pragma unroll
            for (int r = 0; r < 4; ++r)
                bilp[wv * 272 + (quad * 4 + r) * 17 + l15] = accb[r];
        }

        // ---- layer1 MFMA (K=32, features in k=0..7; B zero elsewhere) ----
        #pragma unroll
        for (int m = 0; m < 4; ++m) {
            int mt = wv * 4 + m;
            long long af = *(const long long*)(h1s + (mt * 16 + l15) * 72 + 64);
            f32x4 h[4];
            #pragma unroll
            for (int n = 0; n < 4; ++n)
                h[n] = __builtin_amdgcn_mfma_f32_16x16x32_fp8_fp8(
                    af, w1frag[n], (f32x4){0.f, 0.f, 0.f, 0.f}, 0, 0, 0);
            // silu + pack fp8: position p = l15*4+n holds hidden 16n+l15
            #pragma unroll
            for (int r = 0; r < 4; ++r) {
                float s0 = hsilu(h[0][r]), s1 = hsilu(h[1][r]);
                float s2 = hsilu(h[2][r]), s3 = hsilu(h[3][r]);
                int lo = __builtin_amdgcn_cvt_pk_fp8_f32(s0, s1, 0, false);
                int dw = __builtin_amdgcn_cvt_pk_fp8_f32(s2, s3, lo, true);
                *(int*)(h1s + (mt * 16 + quad * 4 + r) * 72 + l15 * 4) = dw;
            }
        }
        __syncthreads();   // h1 visibility: writes above are cross-lane vs reads below

        // ---- layer2 fp8 MFMA + register epilogue -> gs ----
        #pragma unroll
        for (int tt = 0; tt < 4; ++tt) {
            int tm = wv * 4 + tt;
            unsigned rb = (unsigned)(tm * 16 + l15) * 72 + 8 * quad;
            long long a0 = *(const long long*)(h1s + rb);
            long long a1 = *(const long long*)(h1s + rb + 32);
            f32x4 acc[4];
            #pragma unroll
            for (int n = 0; n < 4; ++n)
                acc[n] = (f32x4){b2c[n], b2c[n], b2c[n], b2c[n]};
            #pragma unroll
            for (int n = 0; n < 4; ++n) {
                acc[n] = __builtin_amdgcn_mfma_f32_16x16x32_fp8_fp8(a0, w2frag[n * 2 + 0], acc[n], 0, 0, 0);
                acc[n] = __builtin_amdgcn_mfma_f32_16x16x32_fp8_fp8(a1, w2frag[n * 2 + 1], acc[n], 0, 0, 0);
            }
            // epilogue: silu, *w3[col], reduce over the 16 cols (l15 lanes)
            float part[4] = {0.f, 0.f, 0.f, 0.f};
            #pragma unroll
            for (int n = 0; n < 4; ++n) {
                #pragma unroll
                for (int r = 0; r < 4; ++r)
                    part[r] = __builtin_fmaf(hsilu(acc[n][r]), w3c[n], part[r]);
            }
            #define SWZ_STEP(pat)                                                              \
                part[0] += __builtin_bit_cast(float, __builtin_amdgcn_ds_swizzle(__builtin_bit_cast(int, part[0]), pat)); \
                part[1] += __builtin_bit_cast(float, __builtin_amdgcn_ds_swizzle(__builtin_bit_cast(int, part[1]), pat)); \
                part[2] += __builtin_bit_cast(float, __builtin_amdgcn_ds_swizzle(__builtin_bit_cast(int, part[2]), pat)); \
                part[3] += __builtin_bit_cast(float, __builtin_amdgcn_ds_swizzle(__builtin_bit_cast(int, part[3]), pat));
            SWZ_STEP(0x041F)
            SWZ_STEP(0x081F)
            SWZ_STEP(0x101F)
            SWZ_STEP(0x201F)
            #undef SWZ_STEP
            // lanes l15<4 write pair p = tm*16 + quad*4 + l15 (no dyn index)
            float v01 = (l15 & 1) ? part[1] : part[0];
            float v23 = (l15 & 1) ? part[3] : part[2];
            float val = (l15 & 2) ? v23 : v01;
            if (l15 < 4)
                gs[tm * 16 + quad * 4 + l15] = val + c0;
        }
        __syncthreads();

        // ---- combine + diag + scatter store ----
        {
            int fq = tid >> 4, fk = tid & 15;
            float logit = bilp[0 * 272 + fq * 17 + fk] + bilp[1 * 272 + fq * 17 + fk]
                        + bilp[2 * 272 + fq * 17 + fk] + bilp[3 * 272 + fq * 17 + fk]
                        + gs[fk * 16 + fq];
            bool valid = (iq * 16 + fq < nb) && (ik * 16 + fk < nb);
            int qi = qlc[(bb << 10) + min(iq * 16 + fq, nb - 1)];
            int ki = qlc[(bb << 10) + min(ik * 16 + fk, nb - 1)];
            if (qi == ki) logit = 0.f;
            if (valid) out[(size_t)((bb << 10) + qi) * 1024 + ki] = logit;
        }
    }
}

extern "C" void kernel_launch(void* const* d_in, const int* in_sizes, int n_in,
                              void* d_out, int out_size, void* d_ws, size_t ws_size,
                              hipStream_t stream) {
    const float* q      = (const float*)d_in[0];   // [4,1024,256]
    const float* coords = (const float*)d_in[1];   // [4,1024,2]
    const int*   amask  = (const int*)d_in[2];     // [4,1024]
    const float* W      = (const float*)d_in[3];   // [256,256]
    const float* w1     = (const float*)d_in[4];   // [6,64]
    const float* b1     = (const float*)d_in[5];   // [64]
    const float* w2     = (const float*)d_in[6];   // [64,64]
    const float* b2     = (const float*)d_in[7];   // [64]
    const float* w3     = (const float*)d_in[8];   // [64,1]
    const float* b3     = (const float*)d_in[9];   // [1]
    const float* bias   = (const float*)d_in[10];  // [1]
    float* out = (float*)d_out;

    char* p = (char*)d_ws;
    unsigned short* qWc  = (unsigned short*)p;  p += 4096 * 256 * 2;  // 2 MB
    unsigned short* qc   = (unsigned short*)p;  p += 4096 * 256 * 2;  // 2 MB
    unsigned short* Wf   = (unsigned short*)p;  p += 8192 * 8 * 2;    // 128 KB
    long long*      w2f  = (long long*)p;       p += 512 * 8;         // 4 KB
    long long*      w1f  = (long long*)p;       p += 256 * 8;         // 2 KB
    int*            qlc  = (int*)p;             p += 4096 * 4;        // 16 KB
    float2*         ccomp= (float2*)p;          p += 4096 * 8;        // 32 KB
    int*            Na   = (int*)p;

    prep_kernel<<<dim3(1063), dim3(256), 0, stream>>>(
        W, w2, w1, b1, amask, coords, out, Wf, w2f, w1f, qlc, ccomp, Na);
    qw_mfma_kernel<<<dim3(64, 4), dim3(256), 0, stream>>>(
        q, Wf, qlc, Na, qWc, qc);
    edge_head_kernel<<<dim3(1024), dim3(256), 0, stream>>>(
        qWc, qc, w2f, w1f, ccomp, qlc, Na, b2, w3, b3, bias, out);
}